// Round 4
// baseline (469.523 us; speedup 1.0000x reference)
//
#include <hip/hip_runtime.h>
#include <hip/hip_bf16.h>

typedef float f32x2 __attribute__((ext_vector_type(2)));

namespace {
enum : int {
  CIN = 64, CMID = 32, COUT = 64,
  H = 128, W = 48, HW = H * W,          // 6144
  HPF = 144, WPF = 64,
  KPSZ = CMID * HPF * WPF,              // 294912 floats
  QSSZ = CMID * HW,                     // 196608 floats
  // attention tiling
  QPT = 6,                              // queries per lane (3 f32x2 pairs)
  QG  = 64 * QPT,                       // 384 queries per block
  NQG = 8,                              // 3072/384 query groups per n
  KVW = 180,                            // kv elems per wave
  SG  = 8,                              // slice groups along kv (8*4*180=5760)
  ACCSZ = 16 * 3072 * 5,                // 245760 floats (additive partials)
  CIGQ = 8,                             // ci split for qkv conv (8 ci each)
  CIGO = 8,                             // ci split for out conv (4 ci each)
};
}

__device__ __forceinline__ float fexp2(float x) { return __builtin_amdgcn_exp2f(x); }

// ---------------------------------------------------------------------------
// Kernel 1: q/k/v 3x3 convs (64->32 ch), ci split 8-ways, fp32 atomic
// accumulation into q_s / kp / vp (all pre-zeroed). q pre-scaled by
// 0.5*log2(e) for exp2-domain softmax. grid (128 y, 2 half, 8 cig) x 192.
// ---------------------------------------------------------------------------
__global__ __launch_bounds__(192) void qkv_conv_kernel(
    const float* __restrict__ x,
    const float* __restrict__ wq, const float* __restrict__ bq,
    const float* __restrict__ wk, const float* __restrict__ bk,
    const float* __restrict__ wv, const float* __restrict__ bv,
    float* __restrict__ q_s, float* __restrict__ kp, float* __restrict__ vp)
{
  __shared__ alignas(16) float xs[3 * 8 * 52];
  const int y = blockIdx.x;
  const int half = blockIdx.y;
  const int cig = blockIdx.z;          // 8 ci per group
  const int tid = threadIdx.x;
  for (int idx = tid; idx < 3 * 8 * 50; idx += 192) {
    int ky = idx / (8 * 50);
    int r = idx - ky * (8 * 50);
    int cil = r / 50;
    int xx = r - cil * 50;
    int gy = y + ky - 1;
    int gx = xx - 1;
    float v = 0.0f;
    if (gy >= 0 && gy < H && (unsigned)gx < (unsigned)W)
      v = x[(cig * 8 + cil) * HW + gy * W + gx];
    xs[(ky * 8 + cil) * 52 + xx] = v;
  }
  __syncthreads();

  const int col = tid >> 2;        // 0..47
  const int xg = tid & 3;          // 0..3
  const int cog = half * 48 + col; // 0..95 : [0,32)=q [32,64)=k [64,96)=v
  const int t = cog >> 5;
  const int cl = cog & 31;
  const float* wsel = (t == 0) ? wq : (t == 1) ? wk : wv;
  const float* bsel = (t == 0) ? bq : (t == 1) ? bk : bv;
  const float* wrowb = wsel + cl * (CIN * 9) + cig * 8 * 9;

  float acc[12];
#pragma unroll
  for (int i = 0; i < 12; ++i) acc[i] = 0.0f;

#pragma unroll 2
  for (int cil = 0; cil < 8; ++cil) {
#pragma unroll
    for (int ky = 0; ky < 3; ++ky) {
      const float* xb = &xs[(ky * 8 + cil) * 52 + xg * 12];
      const float4* p4 = reinterpret_cast<const float4*>(xb);
      float4 r0 = p4[0], r1 = p4[1], r2 = p4[2];
      float xr[14] = {r0.x, r0.y, r0.z, r0.w, r1.x, r1.y, r1.z, r1.w,
                      r2.x, r2.y, r2.z, r2.w, xb[12], xb[13]};
      const float* wr = wrowb + cil * 9 + ky * 3;
#pragma unroll
      for (int kx = 0; kx < 3; ++kx) {
        float wgt = wr[kx];
#pragma unroll
        for (int xx = 0; xx < 12; ++xx)
          acc[xx] = fmaf(wgt, xr[xx + kx], acc[xx]);
      }
    }
  }

  const float bias = (cig == 0) ? bsel[cl] : 0.0f;
  const int x0 = xg * 12;
  if (t == 0) {
#pragma unroll
    for (int xx = 0; xx < 12; ++xx)
      atomicAdd(&q_s[cl * HW + y * W + x0 + xx],
                (acc[xx] + bias) * 0.7213475204444817f);
  } else {
    float* dst = (t == 1) ? kp : vp;
#pragma unroll
    for (int xx = 0; xx < 12; ++xx)
      atomicAdd(&dst[cl * (HPF * WPF) + (y + 8) * WPF + (x0 + xx + 8)],
                acc[xx] + bias);
  }
}

// ---------------------------------------------------------------------------
// Kernel 2: blocked local attention, packed-fp32 (v_pk) math, exp2-domain
// softmax with fixed bias (additive partials). grid (8 qgrp, 8 sgrp, 16 n)
// x 256 threads; 4096 waves = 16 waves/CU, launch_bounds(256,4) keeps
// VGPR<=128 so all 4 waves/SIMD are resident. Wave w stages kv slice
// [(sgrp*4+w)*180, +180) into LDS once, streams it against 6 queries/lane
// (3 query-pairs in f32x2). Block partials merged in LDS then atomicAdd'ed
// into the compact accq accumulator.
// ---------------------------------------------------------------------------
__global__ __launch_bounds__(256, 4) void attn_kernel(
    const float* __restrict__ q_s, const float* __restrict__ kp,
    const float* __restrict__ vp, float* __restrict__ accq)
{
  __shared__ alignas(16) float smem[4 * QG * 5];   // 30720 B (>= tiles 23040)
  float4* tiles = reinterpret_cast<float4*>(smem); // [4][2][KVW]

  const int tid = threadIdx.x;
  const int lane = tid & 63;
  const int w = tid >> 6;
  const int qgrp = blockIdx.x;   // 0..7
  const int sgrp = blockIdx.y;   // 0..7
  const int n = blockIdx.z;      // 0..15
  const int h = n >> 1;
  const int j = n & 1;

  // 3 query-pairs per lane: q2[p][d] = (q_{2p}[d], q_{2p+1}[d])
  f32x2 q2[3][4];
#pragma unroll
  for (int p = 0; p < 3; ++p) {
#pragma unroll
    for (int e = 0; e < 2; ++e) {
      const int qg = qgrp * QG + (2 * p + e) * 64 + lane;
      const int q0 = qg / 24;
      const int q1 = qg - q0 * 24;
      const int qoff = q0 * W + j * 24 + q1;
#pragma unroll
      for (int d = 0; d < 4; ++d)
        q2[p][d][e] = q_s[(h * 4 + d) * HW + qoff];
    }
  }

  // flat-gather base reproducing torch.as_strided semantics
  const int gbase = h * 24576 + j * 24;
  const int mbase = (sgrp * 4 + w) * KVW;

  float4* tk = tiles + (w * 2 + 0) * KVW;
  float4* tv = tiles + (w * 2 + 1) * KVW;
  for (int mt = lane; mt < KVW; mt += 64) {
    const int m = mbase + mt;
    const int m0 = m / 40;
    const int m1 = m - m0 * 40;
    const int off = gbase + m0 * 48 + m1;
    float4 kk, vv;
    kk.x = kp[off];
    kk.y = kp[off + 6144];
    kk.z = kp[off + 12288];
    kk.w = kp[off + 18432];
    vv.x = vp[off];
    vv.y = vp[off + 6144];
    vv.z = vp[off + 12288];
    vv.w = vp[off + 18432];
    tk[mt] = kk;
    tv[mt] = vv;
  }
  asm volatile("s_waitcnt vmcnt(0) lgkmcnt(0)" ::: "memory");

  const f32x2 bias2 = {-16.0f, -16.0f};
  f32x2 lsum2[3];
  f32x2 acc2[3][4];
#pragma unroll
  for (int p = 0; p < 3; ++p) {
    lsum2[p] = (f32x2){0.0f, 0.0f};
#pragma unroll
    for (int d = 0; d < 4; ++d) acc2[p][d] = (f32x2){0.0f, 0.0f};
  }

#pragma unroll 2
  for (int mt = 0; mt < KVW; ++mt) {
    const float4 k4 = tk[mt];
    const float4 v4 = tv[mt];
    const f32x2 kx = {k4.x, k4.x}, ky = {k4.y, k4.y},
                kz = {k4.z, k4.z}, kw = {k4.w, k4.w};
    const f32x2 vx = {v4.x, v4.x}, vy = {v4.y, v4.y},
                vz = {v4.z, v4.z}, vw = {v4.w, v4.w};
#pragma unroll
    for (int p = 0; p < 3; ++p) {
      f32x2 s2 = __builtin_elementwise_fma(q2[p][0], kx, bias2);
      s2 = __builtin_elementwise_fma(q2[p][1], ky, s2);
      s2 = __builtin_elementwise_fma(q2[p][2], kz, s2);
      s2 = __builtin_elementwise_fma(q2[p][3], kw, s2);
      f32x2 p2;
      p2.x = fexp2(s2.x);
      p2.y = fexp2(s2.y);
      lsum2[p] += p2;
      acc2[p][0] = __builtin_elementwise_fma(p2, vx, acc2[p][0]);
      acc2[p][1] = __builtin_elementwise_fma(p2, vy, acc2[p][1]);
      acc2[p][2] = __builtin_elementwise_fma(p2, vz, acc2[p][2]);
      acc2[p][3] = __builtin_elementwise_fma(p2, vw, acc2[p][3]);
    }
  }

  // in-block merge: 4 waves -> 1 partial set, then atomicAdd to accq
  __syncthreads();   // done reading tiles; smem becomes merge buffer
#pragma unroll
  for (int p = 0; p < 3; ++p) {
#pragma unroll
    for (int e = 0; e < 2; ++e) {
      float* mb = &smem[w * (QG * 5) + (2 * p + e) * 5 * 64 + lane];
      mb[0]   = lsum2[p][e];
      mb[64]  = acc2[p][0][e];
      mb[128] = acc2[p][1][e];
      mb[192] = acc2[p][2][e];
      mb[256] = acc2[p][3][e];
    }
  }
  __syncthreads();
  const int qbase = n * 3072 + qgrp * QG;
  for (int id = tid; id < QG * 5; id += 256) {
    const float val = smem[id] + smem[QG * 5 + id] + smem[2 * QG * 5 + id] +
                      smem[3 * QG * 5 + id];
    const int qq = (id / 320) * 64 + (id & 63);
    const int c = (id % 320) >> 6;
    atomicAdd(&accq[(qbase + qq) * 5 + c], val);
  }
}

// ---------------------------------------------------------------------------
// Kernel 2b: normalize accq -> o_mid. 16*3072 queries, one thread each.
// ---------------------------------------------------------------------------
__global__ __launch_bounds__(256) void normalize_kernel(
    const float* __restrict__ accq, float* __restrict__ o_mid)
{
  const int idx = blockIdx.x * 256 + threadIdx.x;   // 0..49151
  const int n = idx / 3072;
  const int qg = idx - n * 3072;
  const int h = n >> 1;
  const int j = n & 1;
  const float* a = accq + (size_t)idx * 5;
  const float inv = 1.0f / a[0];
  const int q0 = qg / 24;
  const int q1 = qg - q0 * 24;
  const int qoff = q0 * W + j * 24 + q1;
  o_mid[(h * 4 + 0) * HW + qoff] = a[1] * inv;
  o_mid[(h * 4 + 1) * HW + qoff] = a[2] * inv;
  o_mid[(h * 4 + 2) * HW + qoff] = a[3] * inv;
  o_mid[(h * 4 + 3) * HW + qoff] = a[4] * inv;
}

// ---------------------------------------------------------------------------
// Kernel 3: output 3x3 conv (32 -> 64 ch), ci split 8-ways, atomic into out.
// grid (128 y, 2 half, 8 cig) x 128 threads.
// ---------------------------------------------------------------------------
__global__ __launch_bounds__(128) void out_conv_kernel(
    const float* __restrict__ o_mid, const float* __restrict__ wo,
    float* __restrict__ out)
{
  __shared__ alignas(16) float xs[3 * 4 * 52];
  const int y = blockIdx.x;
  const int half = blockIdx.y;
  const int cig = blockIdx.z;          // 4 ci per group
  const int tid = threadIdx.x;
  for (int idx = tid; idx < 3 * 4 * 50; idx += 128) {
    int ky = idx / (4 * 50);
    int r = idx - ky * (4 * 50);
    int cil = r / 50;
    int xx = r - cil * 50;
    int gy = y + ky - 1;
    int gx = xx - 1;
    float v = 0.0f;
    if (gy >= 0 && gy < H && (unsigned)gx < (unsigned)W)
      v = o_mid[(cig * 4 + cil) * HW + gy * W + gx];
    xs[(ky * 4 + cil) * 52 + xx] = v;
  }
  __syncthreads();

  const int col = tid >> 2;
  const int xg = tid & 3;
  const int co = half * 32 + col;
  const float* wrowb = wo + co * (CMID * 9) + cig * 4 * 9;
  float acc[12];
#pragma unroll
  for (int i = 0; i < 12; ++i) acc[i] = 0.0f;

#pragma unroll
  for (int cil = 0; cil < 4; ++cil) {
#pragma unroll
    for (int ky = 0; ky < 3; ++ky) {
      const float* xb = &xs[(ky * 4 + cil) * 52 + xg * 12];
      const float4* p4 = reinterpret_cast<const float4*>(xb);
      float4 r0 = p4[0], r1 = p4[1], r2 = p4[2];
      float xr[14] = {r0.x, r0.y, r0.z, r0.w, r1.x, r1.y, r1.z, r1.w,
                      r2.x, r2.y, r2.z, r2.w, xb[12], xb[13]};
      const float* wr = wrowb + cil * 9 + ky * 3;
#pragma unroll
      for (int kx = 0; kx < 3; ++kx) {
        float wgt = wr[kx];
#pragma unroll
        for (int xx = 0; xx < 12; ++xx)
          acc[xx] = fmaf(wgt, xr[xx + kx], acc[xx]);
      }
    }
  }

  const int x0 = xg * 12;
#pragma unroll
  for (int xx = 0; xx < 12; ++xx)
    atomicAdd(&out[co * HW + y * W + x0 + xx], acc[xx]);
}

// ---------------------------------------------------------------------------
extern "C" void kernel_launch(void* const* d_in, const int* in_sizes, int n_in,
                              void* d_out, int out_size, void* d_ws, size_t ws_size,
                              hipStream_t stream) {
  const float* x  = (const float*)d_in[0];
  const float* wq = (const float*)d_in[1];
  const float* bq = (const float*)d_in[2];
  const float* wk = (const float*)d_in[3];
  const float* bk = (const float*)d_in[4];
  const float* wv = (const float*)d_in[5];
  const float* bv = (const float*)d_in[6];
  const float* wo = (const float*)d_in[7];
  float* out = (float*)d_out;

  // ws layout (floats):
  // q_s[196608] | kp[294912] | vp[294912] | accq[245760] | o_mid[196608]
  float* q_s   = (float*)d_ws;
  float* kp    = q_s + QSSZ;
  float* vp    = kp + KPSZ;
  float* accq  = vp + KPSZ;
  float* o_mid = accq + ACCSZ;

  // zero everything that is atomically accumulated (q_s..accq contiguous)
  hipMemsetAsync((void*)q_s, 0,
                 (size_t)(QSSZ + 2 * KPSZ + ACCSZ) * sizeof(float), stream);
  hipMemsetAsync((void*)out, 0, (size_t)(COUT * HW) * sizeof(float), stream);

  qkv_conv_kernel<<<dim3(128, 2, CIGQ), 192, 0, stream>>>(
      x, wq, bq, wk, bk, wv, bv, q_s, kp, vp);
  attn_kernel<<<dim3(NQG, SG, 16), 256, 0, stream>>>(q_s, kp, vp, accq);
  normalize_kernel<<<dim3(16 * 3072 / 256), 256, 0, stream>>>(accq, o_mid);
  out_conv_kernel<<<dim3(128, 2, CIGO), 128, 0, stream>>>(o_mid, wo, out);
}

// Round 5
// 173.483 us; speedup vs baseline: 2.7064x; 2.7064x over previous
//
#include <hip/hip_runtime.h>
#include <hip/hip_bf16.h>

typedef float f32x2 __attribute__((ext_vector_type(2)));

namespace {
enum : int {
  CIN = 64, CMID = 32, COUT = 64,
  H = 128, W = 48, HW = H * W,          // 6144
  HPF = 144, WPF = 64,
  KPSZ = CMID * HPF * WPF,              // 294912 floats
  QSSZ = CMID * HW,                     // 196608 floats
  // attention tiling
  QPT = 6,                              // queries per lane (3 f32x2 pairs)
  QG  = 64 * QPT,                       // 384 queries per block
  NQG = 8,                              // 3072/384 query groups per n
  KVW = 180,                            // kv elems per wave
  SG  = 8,                              // slice groups along kv (8*4*180=5760)
  PARTSZ = 16 * NQG * SG * QG * 5,      // 1,966,080 floats
  CIGQ = 4,                             // qkv conv ci split (16 ci each)
  CIGO = 4,                             // out conv ci split (8 ci each)
  QPARTSZ = CIGQ * 96 * HW,             // 2,359,296 floats
};
}

__device__ __forceinline__ float fexp2(float x) { return __builtin_amdgcn_exp2f(x); }

// ---------------------------------------------------------------------------
// Kernel 1: q/k/v 3x3 convs (64->32 ch), ci split 4-ways, NON-atomic partial
// planes. grid (128 y, 2 half, 4 cig) x 192 threads -> 12 waves/CU.
// ---------------------------------------------------------------------------
__global__ __launch_bounds__(192) void qkv_conv_kernel(
    const float* __restrict__ x,
    const float* __restrict__ wq, const float* __restrict__ wk,
    const float* __restrict__ wv, float* __restrict__ qpart)
{
  __shared__ alignas(16) float xs[3 * 16 * 52];
  const int y = blockIdx.x;
  const int half = blockIdx.y;
  const int cig = blockIdx.z;          // 16 ci per group
  const int tid = threadIdx.x;
  for (int idx = tid; idx < 3 * 16 * 50; idx += 192) {
    int ky = idx / (16 * 50);
    int r = idx - ky * (16 * 50);
    int cil = r / 50;
    int xx = r - cil * 50;
    int gy = y + ky - 1;
    int gx = xx - 1;
    float v = 0.0f;
    if (gy >= 0 && gy < H && (unsigned)gx < (unsigned)W)
      v = x[(cig * 16 + cil) * HW + gy * W + gx];
    xs[(ky * 16 + cil) * 52 + xx] = v;
  }
  __syncthreads();

  const int col = tid >> 2;        // 0..47
  const int xg = tid & 3;          // 0..3
  const int cog = half * 48 + col; // 0..95 : [0,32)=q [32,64)=k [64,96)=v
  const int t = cog >> 5;
  const int cl = cog & 31;
  const float* wsel = (t == 0) ? wq : (t == 1) ? wk : wv;
  const float* wrowb = wsel + cl * (CIN * 9) + cig * 16 * 9;

  float acc[12];
#pragma unroll
  for (int i = 0; i < 12; ++i) acc[i] = 0.0f;

#pragma unroll 4
  for (int cil = 0; cil < 16; ++cil) {
#pragma unroll
    for (int ky = 0; ky < 3; ++ky) {
      const float* xb = &xs[(ky * 16 + cil) * 52 + xg * 12];
      const float4* p4 = reinterpret_cast<const float4*>(xb);
      float4 r0 = p4[0], r1 = p4[1], r2 = p4[2];
      float xr[14] = {r0.x, r0.y, r0.z, r0.w, r1.x, r1.y, r1.z, r1.w,
                      r2.x, r2.y, r2.z, r2.w, xb[12], xb[13]};
      const float* wr = wrowb + cil * 9 + ky * 3;
#pragma unroll
      for (int kx = 0; kx < 3; ++kx) {
        float wgt = wr[kx];
#pragma unroll
        for (int xx = 0; xx < 12; ++xx)
          acc[xx] = fmaf(wgt, xr[xx + kx], acc[xx]);
      }
    }
  }

  const int x0 = xg * 12;
  float* dst = &qpart[(size_t)(cig * 96 + cog) * HW + y * W + x0];
#pragma unroll
  for (int xx = 0; xx < 12; ++xx) dst[xx] = acc[xx];
}

// ---------------------------------------------------------------------------
// Kernel 1b: reduce 4 ci-partials, apply bias (+ exp2-domain scale for q),
// scatter into q_s / flange-padded kp,vp. float4 per thread.
// ---------------------------------------------------------------------------
__global__ __launch_bounds__(256) void qkv_reduce_kernel(
    const float* __restrict__ qpart,
    const float* __restrict__ bq, const float* __restrict__ bk,
    const float* __restrict__ bv,
    float* __restrict__ q_s, float* __restrict__ kp, float* __restrict__ vp)
{
  const int fidx = blockIdx.x * 256 + threadIdx.x;  // 0..147455 (96ch*1536)
  const int cog = fidx / 1536;
  const int p4 = fidx - cog * 1536;
  const float4* src = reinterpret_cast<const float4*>(qpart) + cog * 1536 + p4;
  float4 s = src[0];
  const float4 s1 = src[96 * 1536], s2 = src[2 * 96 * 1536], s3 = src[3 * 96 * 1536];
  s.x += s1.x + s2.x + s3.x;
  s.y += s1.y + s2.y + s3.y;
  s.z += s1.z + s2.z + s3.z;
  s.w += s1.w + s2.w + s3.w;

  const int pix = p4 * 4;
  const int y = pix / W;
  const int x = pix - y * W;
  if (cog < 32) {
    const float b = bq[cog];
    const float c = 0.7213475204444817f;   // 0.5 * log2(e)
    float4 o = {(s.x + b) * c, (s.y + b) * c, (s.z + b) * c, (s.w + b) * c};
    reinterpret_cast<float4*>(q_s)[cog * 1536 + p4] = o;
  } else {
    const int cl = cog & 31;
    const float b = (cog < 64) ? bk[cl] : bv[cl];
    float* dst = (cog < 64) ? kp : vp;
    float4 o = {s.x + b, s.y + b, s.z + b, s.w + b};
    *reinterpret_cast<float4*>(&dst[cl * (HPF * WPF) + (y + 8) * WPF + (x + 8)]) = o;
  }
}

// ---------------------------------------------------------------------------
// Kernel 2: blocked local attention, packed-fp32 math, exp2-domain softmax
// with fixed bias (additive partials). grid (8 qgrp, 8 sgrp, 16 n) x 256.
// 4096 waves, launch_bounds(256,4) -> 16 waves/CU. Non-atomic partial out.
// ---------------------------------------------------------------------------
__global__ __launch_bounds__(256, 4) void attn_kernel(
    const float* __restrict__ q_s, const float* __restrict__ kp,
    const float* __restrict__ vp, float* __restrict__ part)
{
  __shared__ alignas(16) float smem[4 * QG * 5];   // 30720 B (>= tiles 23040)
  float4* tiles = reinterpret_cast<float4*>(smem); // [4][2][KVW]

  const int tid = threadIdx.x;
  const int lane = tid & 63;
  const int w = tid >> 6;
  const int qgrp = blockIdx.x;   // 0..7
  const int sgrp = blockIdx.y;   // 0..7
  const int n = blockIdx.z;      // 0..15
  const int h = n >> 1;
  const int j = n & 1;

  // 3 query-pairs per lane: q2[p][d] = (q_{2p}[d], q_{2p+1}[d])
  f32x2 q2[3][4];
#pragma unroll
  for (int p = 0; p < 3; ++p) {
#pragma unroll
    for (int e = 0; e < 2; ++e) {
      const int qg = qgrp * QG + (2 * p + e) * 64 + lane;
      const int q0 = qg / 24;
      const int q1 = qg - q0 * 24;
      const int qoff = q0 * W + j * 24 + q1;
#pragma unroll
      for (int d = 0; d < 4; ++d)
        q2[p][d][e] = q_s[(h * 4 + d) * HW + qoff];
    }
  }

  // flat-gather base reproducing torch.as_strided semantics
  const int gbase = h * 24576 + j * 24;
  const int mbase = (sgrp * 4 + w) * KVW;

  float4* tk = tiles + (w * 2 + 0) * KVW;
  float4* tv = tiles + (w * 2 + 1) * KVW;
  for (int mt = lane; mt < KVW; mt += 64) {
    const int m = mbase + mt;
    const int m0 = m / 40;
    const int m1 = m - m0 * 40;
    const int off = gbase + m0 * 48 + m1;
    float4 kk, vv;
    kk.x = kp[off];
    kk.y = kp[off + 6144];
    kk.z = kp[off + 12288];
    kk.w = kp[off + 18432];
    vv.x = vp[off];
    vv.y = vp[off + 6144];
    vv.z = vp[off + 12288];
    vv.w = vp[off + 18432];
    tk[mt] = kk;
    tv[mt] = vv;
  }
  asm volatile("s_waitcnt vmcnt(0) lgkmcnt(0)" ::: "memory");

  const f32x2 bias2 = {-16.0f, -16.0f};
  f32x2 lsum2[3];
  f32x2 acc2[3][4];
#pragma unroll
  for (int p = 0; p < 3; ++p) {
    lsum2[p] = (f32x2){0.0f, 0.0f};
#pragma unroll
    for (int d = 0; d < 4; ++d) acc2[p][d] = (f32x2){0.0f, 0.0f};
  }

#pragma unroll 2
  for (int mt = 0; mt < KVW; ++mt) {
    const float4 k4 = tk[mt];
    const float4 v4 = tv[mt];
    const f32x2 kx = {k4.x, k4.x}, ky = {k4.y, k4.y},
                kz = {k4.z, k4.z}, kw = {k4.w, k4.w};
    const f32x2 vx = {v4.x, v4.x}, vy = {v4.y, v4.y},
                vz = {v4.z, v4.z}, vw = {v4.w, v4.w};
#pragma unroll
    for (int p = 0; p < 3; ++p) {
      f32x2 s2 = __builtin_elementwise_fma(q2[p][0], kx, bias2);
      s2 = __builtin_elementwise_fma(q2[p][1], ky, s2);
      s2 = __builtin_elementwise_fma(q2[p][2], kz, s2);
      s2 = __builtin_elementwise_fma(q2[p][3], kw, s2);
      f32x2 p2;
      p2.x = fexp2(s2.x);
      p2.y = fexp2(s2.y);
      lsum2[p] += p2;
      acc2[p][0] = __builtin_elementwise_fma(p2, vx, acc2[p][0]);
      acc2[p][1] = __builtin_elementwise_fma(p2, vy, acc2[p][1]);
      acc2[p][2] = __builtin_elementwise_fma(p2, vz, acc2[p][2]);
      acc2[p][3] = __builtin_elementwise_fma(p2, vw, acc2[p][3]);
    }
  }

  // in-block merge: 4 waves -> 1 partial set (non-atomic global write)
  __syncthreads();   // done reading tiles; smem becomes merge buffer
#pragma unroll
  for (int p = 0; p < 3; ++p) {
#pragma unroll
    for (int e = 0; e < 2; ++e) {
      float* mb = &smem[w * (QG * 5) + (2 * p + e) * 5 * 64 + lane];
      mb[0]   = lsum2[p][e];
      mb[64]  = acc2[p][0][e];
      mb[128] = acc2[p][1][e];
      mb[192] = acc2[p][2][e];
      mb[256] = acc2[p][3][e];
    }
  }
  __syncthreads();
  float* pout = part + (size_t)((n * NQG + qgrp) * SG + sgrp) * (QG * 5);
  for (int id = tid; id < QG * 5; id += 256)
    pout[id] = smem[id] + smem[QG * 5 + id] + smem[2 * QG * 5 + id] +
               smem[3 * QG * 5 + id];
}

// ---------------------------------------------------------------------------
// Kernel 2b: merge SG slice-group partials + normalize -> o_mid.
// grid (NQG, 16) x 384 threads; thread = one query.
// ---------------------------------------------------------------------------
__global__ __launch_bounds__(384) void merge_kernel(
    const float* __restrict__ part, float* __restrict__ o_mid)
{
  const int tid = threadIdx.x;
  const int qi = tid >> 6;
  const int lane = tid & 63;
  const int qgrp = blockIdx.x;
  const int n = blockIdx.y;
  const int h = n >> 1;
  const int j = n & 1;

  const float* pb = part + (size_t)((n * NQG + qgrp) * SG) * (QG * 5) +
                    qi * 5 * 64 + lane;
  float L = 0.0f, A0 = 0.0f, A1 = 0.0f, A2 = 0.0f, A3 = 0.0f;
#pragma unroll
  for (int s = 0; s < SG; ++s) {
    const float* p = pb + s * (QG * 5);
    L  += p[0];
    A0 += p[64];
    A1 += p[128];
    A2 += p[192];
    A3 += p[256];
  }
  const float inv = 1.0f / L;
  const int qg = qgrp * QG + qi * 64 + lane;
  const int q0 = qg / 24;
  const int q1 = qg - q0 * 24;
  const int qoff = q0 * W + j * 24 + q1;
  o_mid[(h * 4 + 0) * HW + qoff] = A0 * inv;
  o_mid[(h * 4 + 1) * HW + qoff] = A1 * inv;
  o_mid[(h * 4 + 2) * HW + qoff] = A2 * inv;
  o_mid[(h * 4 + 3) * HW + qoff] = A3 * inv;
}

// ---------------------------------------------------------------------------
// Kernel 3: output 3x3 conv (32->64 ch), ci split 4-ways, non-atomic
// partials. grid (128 y, 2 half, 4 cig) x 128 threads.
// ---------------------------------------------------------------------------
__global__ __launch_bounds__(128) void out_conv_kernel(
    const float* __restrict__ o_mid, const float* __restrict__ wo,
    float* __restrict__ opart)
{
  __shared__ alignas(16) float xs[3 * 8 * 52];
  const int y = blockIdx.x;
  const int half = blockIdx.y;
  const int cig = blockIdx.z;          // 8 ci per group
  const int tid = threadIdx.x;
  for (int idx = tid; idx < 3 * 8 * 50; idx += 128) {
    int ky = idx / (8 * 50);
    int r = idx - ky * (8 * 50);
    int cil = r / 50;
    int xx = r - cil * 50;
    int gy = y + ky - 1;
    int gx = xx - 1;
    float v = 0.0f;
    if (gy >= 0 && gy < H && (unsigned)gx < (unsigned)W)
      v = o_mid[(cig * 8 + cil) * HW + gy * W + gx];
    xs[(ky * 8 + cil) * 52 + xx] = v;
  }
  __syncthreads();

  const int col = tid >> 2;
  const int xg = tid & 3;
  const int co = half * 32 + col;
  const float* wrowb = wo + co * (CMID * 9) + cig * 8 * 9;
  float acc[12];
#pragma unroll
  for (int i = 0; i < 12; ++i) acc[i] = 0.0f;

#pragma unroll 2
  for (int cil = 0; cil < 8; ++cil) {
#pragma unroll
    for (int ky = 0; ky < 3; ++ky) {
      const float* xb = &xs[(ky * 8 + cil) * 52 + xg * 12];
      const float4* p4 = reinterpret_cast<const float4*>(xb);
      float4 r0 = p4[0], r1 = p4[1], r2 = p4[2];
      float xr[14] = {r0.x, r0.y, r0.z, r0.w, r1.x, r1.y, r1.z, r1.w,
                      r2.x, r2.y, r2.z, r2.w, xb[12], xb[13]};
      const float* wr = wrowb + cil * 9 + ky * 3;
#pragma unroll
      for (int kx = 0; kx < 3; ++kx) {
        float wgt = wr[kx];
#pragma unroll
        for (int xx = 0; xx < 12; ++xx)
          acc[xx] = fmaf(wgt, xr[xx + kx], acc[xx]);
      }
    }
  }

  const int x0 = xg * 12;
  float* dst = &opart[(size_t)(cig * 64 + co) * HW + y * W + x0];
#pragma unroll
  for (int xx = 0; xx < 12; ++xx) dst[xx] = acc[xx];
}

// ---------------------------------------------------------------------------
// Kernel 3b: reduce 4 out-conv partials -> final output. float4 per thread.
// ---------------------------------------------------------------------------
__global__ __launch_bounds__(256) void out_reduce_kernel(
    const float* __restrict__ opart, float* __restrict__ out)
{
  const int fidx = blockIdx.x * 256 + threadIdx.x;  // 0..98303 (64ch*1536)
  const float4* src = reinterpret_cast<const float4*>(opart) + fidx;
  float4 s = src[0];
  const float4 s1 = src[64 * 1536], s2 = src[2 * 64 * 1536], s3 = src[3 * 64 * 1536];
  s.x += s1.x + s2.x + s3.x;
  s.y += s1.y + s2.y + s3.y;
  s.z += s1.z + s2.z + s3.z;
  s.w += s1.w + s2.w + s3.w;
  reinterpret_cast<float4*>(out)[fidx] = s;
}

// ---------------------------------------------------------------------------
extern "C" void kernel_launch(void* const* d_in, const int* in_sizes, int n_in,
                              void* d_out, int out_size, void* d_ws, size_t ws_size,
                              hipStream_t stream) {
  const float* x  = (const float*)d_in[0];
  const float* wq = (const float*)d_in[1];
  const float* bq = (const float*)d_in[2];
  const float* wk = (const float*)d_in[3];
  const float* bk = (const float*)d_in[4];
  const float* wv = (const float*)d_in[5];
  const float* bv = (const float*)d_in[6];
  const float* wo = (const float*)d_in[7];
  float* out = (float*)d_out;

  // ws layout (floats):
  // q_s[196608] | kp[294912] | vp[294912] | o_mid[196608] | apart[1966080]
  // | qpart[2359296] (opart aliases qpart - phases are stream-ordered)
  float* q_s   = (float*)d_ws;
  float* kp    = q_s + QSSZ;
  float* vp    = kp + KPSZ;
  float* o_mid = vp + KPSZ;
  float* apart = o_mid + QSSZ;
  float* qpart = apart + PARTSZ;
  float* opart = qpart;

  // zero only the flange padding regions of kp/vp (interiors fully written)
  hipMemsetAsync((void*)kp, 0, (size_t)(2 * KPSZ) * sizeof(float), stream);

  qkv_conv_kernel<<<dim3(128, 2, CIGQ), 192, 0, stream>>>(x, wq, wk, wv, qpart);
  qkv_reduce_kernel<<<dim3(576), 256, 0, stream>>>(qpart, bq, bk, bv,
                                                   q_s, kp, vp);
  attn_kernel<<<dim3(NQG, SG, 16), 256, 0, stream>>>(q_s, kp, vp, apart);
  merge_kernel<<<dim3(NQG, 16), 384, 0, stream>>>(apart, o_mid);
  out_conv_kernel<<<dim3(128, 2, CIGO), 128, 0, stream>>>(o_mid, wo, opart);
  out_reduce_kernel<<<dim3(384), 256, 0, stream>>>(opart, out);
}